// Round 6
// baseline (495.223 us; speedup 1.0000x reference)
//
#include <hip/hip_runtime.h>

typedef __bf16 bf16;
typedef __bf16 bf16x4 __attribute__((ext_vector_type(4)));
typedef __bf16 bf16x8 __attribute__((ext_vector_type(8)));
typedef float f32x4 __attribute__((ext_vector_type(4)));

__device__ __forceinline__ f32x4 MFMA16(bf16x8 a, bf16x8 b, f32x4 c) {
  return __builtin_amdgcn_mfma_f32_16x16x32_bf16(a, b, c, 0, 0, 0);
}

__device__ __forceinline__ bf16 split_hi(float v) { return (bf16)v; }
__device__ __forceinline__ bf16 split_lo(float v) { return (bf16)(v - (float)(bf16)v); }

// ---- f32 -> bf16 bulk convert (n % 4 == 0) ----
__global__ void k_cvt(const float* __restrict__ in, bf16* __restrict__ out, long n) {
  const long i = ((long)blockIdx.x * 256 + threadIdx.x) * 4;
  if (i < n) {
    const f32x4 v = *(const f32x4*)&in[i];
    bf16x4 o;
#pragma unroll
    for (int j = 0; j < 4; ++j) o[j] = (bf16)v[j];
    *(bf16x4*)&out[i] = o;
  }
}

// ---- Wc[b][d][r] = sum_k w[b,k] * neurons[idx[b,k]][d][r]  (f32 out) ----
__global__ void k_build_wc(const float* __restrict__ neurons, const float* __restrict__ w,
                           const int* __restrict__ idx, float* __restrict__ Wc) {
  const int d = blockIdx.x, b = blockIdx.y, r = threadIdx.x;
  float acc = 0.f;
#pragma unroll
  for (int k = 0; k < 16; ++k) {
    const float wk = w[b * 16 + k];
    const int ni = idx[b * 16 + k];
    acc += wk * neurons[((long)ni * 1024 + d) * 128 + r];
  }
  Wc[((long)b * 1024 + d) * 128 + r] = acc;
}

// ---- Wn[z=which*8+b][r][d] = sum_k w[b,k] * pool[idx[b,k]][r][d]  (f32 out) ----
__global__ void k_build_mix(const float* __restrict__ pool,
                            const float* __restrict__ wq, const int* __restrict__ iq,
                            const float* __restrict__ wk, const int* __restrict__ ik,
                            const float* __restrict__ wv, const int* __restrict__ iv,
                            float* __restrict__ Wn) {
  const int d = blockIdx.x * 256 + threadIdx.x;
  const int r = blockIdx.y;
  const int z = blockIdx.z, which = z >> 3, b = z & 7;
  const float* wp = which == 0 ? wq : (which == 1 ? wk : wv);
  const int* ip = which == 0 ? iq : (which == 1 ? ik : iv);
  float acc = 0.f;
#pragma unroll
  for (int k = 0; k < 8; ++k) {
    const float wkk = wp[b * 8 + k];
    const int ni = ip[b * 8 + k];
    acc += wkk * pool[((long)ni * 128 + r) * 1024 + d];
  }
  Wn[((long)z * 128 + r) * 1024 + d] = acc;
}

// ---- batched transpose [M][N] -> [N][M] (z = batch) ----
template <typename T>
__global__ void k_transpose(const T* __restrict__ in, T* __restrict__ out, int M, int N) {
  __shared__ T t[64][65];
  const int n0 = blockIdx.x * 64, m0 = blockIdx.y * 64;
  const long base = (long)blockIdx.z * M * N;
  const int tid = threadIdx.x;
#pragma unroll
  for (int i = 0; i < 16; ++i) {
    const int lin = i * 256 + tid;
    const int r = lin >> 6, c = lin & 63;
    t[r][c] = in[base + (long)(m0 + r) * N + (n0 + c)];
  }
  __syncthreads();
#pragma unroll
  for (int i = 0; i < 16; ++i) {
    const int lin = i * 256 + tid;
    const int r = lin >> 6, c = lin & 63;
    out[base + (long)(n0 + r) * M + (m0 + c)] = t[c][r];
  }
}

// ---- split-precision GEMM: C = A(MxK,f32) * B(KxN) with Bt[n][k] f32.
// A,B split into bf16 hi+lo in LDS; 3 MFMAs (hh + hl + lh) per tile -> ~fp32 scores.
// Out f32 (f32_out) or bf16; head-split option. BM=BN=64, 4 waves 2x2.
__global__ __launch_bounds__(256) void k_gemm_split(
    const float* __restrict__ A, const float* __restrict__ Bt, void* __restrict__ C,
    int M, int N, int K, long sA, long sB, long sC, int split_heads, int f32_out) {
  constexpr int BM = 64, BN = 64, BK = 32, LDR = 40;
  __shared__ __align__(16) bf16 Ash[BM * LDR], Asl[BM * LDR];
  __shared__ __align__(16) bf16 Bsh[BN * LDR], Bsl[BN * LDR];
  const int tid = threadIdx.x, wave = tid >> 6, lane = tid & 63;
  const int quad = lane >> 4, l16 = lane & 15;
  const int wrow = wave >> 1, wcol = wave & 1;
  const int z = blockIdx.z;
  const float* Ap = A + (long)z * sA;
  const float* Bp = Bt + (long)z * sB;
  const long m0 = (long)blockIdx.y * BM, n0 = (long)blockIdx.x * BN;
  f32x4 acc[2][2];
#pragma unroll
  for (int mt = 0; mt < 2; ++mt)
#pragma unroll
    for (int nt = 0; nt < 2; ++nt) acc[mt][nt] = (f32x4){0.f, 0.f, 0.f, 0.f};
  for (int k0 = 0; k0 < K; k0 += BK) {
#pragma unroll
    for (int i = 0; i < 2; ++i) {  // A: 64 rows x 32 k, f32x4 per thread x2
      const int c = i * 256 + tid, r = c >> 3, c4 = c & 7;
      const f32x4 v = *(const f32x4*)&Ap[(m0 + r) * K + k0 + c4 * 4];
      bf16x4 h4, l4;
#pragma unroll
      for (int j = 0; j < 4; ++j) { h4[j] = split_hi(v[j]); l4[j] = split_lo(v[j]); }
      *(bf16x4*)&Ash[r * LDR + c4 * 4] = h4;
      *(bf16x4*)&Asl[r * LDR + c4 * 4] = l4;
    }
#pragma unroll
    for (int i = 0; i < 2; ++i) {
      const int c = i * 256 + tid, r = c >> 3, c4 = c & 7;
      const f32x4 v = *(const f32x4*)&Bp[(n0 + r) * K + k0 + c4 * 4];
      bf16x4 h4, l4;
#pragma unroll
      for (int j = 0; j < 4; ++j) { h4[j] = split_hi(v[j]); l4[j] = split_lo(v[j]); }
      *(bf16x4*)&Bsh[r * LDR + c4 * 4] = h4;
      *(bf16x4*)&Bsl[r * LDR + c4 * 4] = l4;
    }
    __syncthreads();
    bf16x8 ah[2], al[2], bh[2], bl[2];
#pragma unroll
    for (int mt = 0; mt < 2; ++mt) {
      const int row = wrow * 32 + mt * 16 + l16;
      ah[mt] = *(const bf16x8*)&Ash[row * LDR + quad * 8];
      al[mt] = *(const bf16x8*)&Asl[row * LDR + quad * 8];
    }
#pragma unroll
    for (int nt = 0; nt < 2; ++nt) {
      const int row = wcol * 32 + nt * 16 + l16;
      bh[nt] = *(const bf16x8*)&Bsh[row * LDR + quad * 8];
      bl[nt] = *(const bf16x8*)&Bsl[row * LDR + quad * 8];
    }
#pragma unroll
    for (int mt = 0; mt < 2; ++mt)
#pragma unroll
      for (int nt = 0; nt < 2; ++nt) {
        acc[mt][nt] = MFMA16(ah[mt], bh[nt], acc[mt][nt]);
        acc[mt][nt] = MFMA16(ah[mt], bl[nt], acc[mt][nt]);
        acc[mt][nt] = MFMA16(al[mt], bh[nt], acc[mt][nt]);
      }
    __syncthreads();
  }
  bf16* Cb = (bf16*)C + (long)z * sC;
  float* Cf = (float*)C + (long)z * sC;
#pragma unroll
  for (int mt = 0; mt < 2; ++mt)
#pragma unroll
    for (int nt = 0; nt < 2; ++nt)
#pragma unroll
      for (int r = 0; r < 4; ++r) {
        const long row = m0 + wrow * 32 + mt * 16 + quad * 4 + r;
        const long col = n0 + wcol * 32 + nt * 16 + l16;
        const float v = acc[mt][nt][r];
        const long off = split_heads
                             ? ((col >> 6) * ((long)M * 64) + row * 64 + (col & 63))
                             : (row * (long)N + col);
        if (f32_out) Cf[off] = v;
        else Cb[off] = (bf16)v;
      }
}

// ---- plain bf16 GEMM for the output projection: C = A(MxK) * Bt[n][k], out f32. ----
template <int BM, int BN>
__global__ __launch_bounds__(256) void k_gemm_bt(
    const bf16* __restrict__ A, const bf16* __restrict__ Bt, float* __restrict__ C,
    int M, int N, int K) {
  constexpr int BK = 32, LDR = BK + 8;
  constexpr int MT = BM / 32, NT = BN / 32;
  __shared__ __align__(16) bf16 As[BM * LDR];
  __shared__ __align__(16) bf16 Bs[BN * LDR];
  const int tid = threadIdx.x, wave = tid >> 6, lane = tid & 63;
  const int quad = lane >> 4, l16 = lane & 15;
  const int wrow = wave >> 1, wcol = wave & 1;
  const long m0 = (long)blockIdx.y * BM, n0 = (long)blockIdx.x * BN;
  f32x4 acc[MT][NT];
#pragma unroll
  for (int mt = 0; mt < MT; ++mt)
#pragma unroll
    for (int nt = 0; nt < NT; ++nt) acc[mt][nt] = (f32x4){0.f, 0.f, 0.f, 0.f};
  constexpr int ACH = BM * BK / 8 / 256;
  constexpr int BCH = BN * BK / 8 / 256;
  for (int k0 = 0; k0 < K; k0 += BK) {
#pragma unroll
    for (int i = 0; i < ACH; ++i) {
      const int c = i * 256 + tid, r = c >> 2, c4 = c & 3;
      *(bf16x8*)&As[r * LDR + c4 * 8] = *(const bf16x8*)&A[(m0 + r) * K + k0 + c4 * 8];
    }
#pragma unroll
    for (int i = 0; i < BCH; ++i) {
      const int c = i * 256 + tid, r = c >> 2, c4 = c & 3;
      *(bf16x8*)&Bs[r * LDR + c4 * 8] = *(const bf16x8*)&Bt[(n0 + r) * K + k0 + c4 * 8];
    }
    __syncthreads();
    bf16x8 af[MT], bfr[NT];
#pragma unroll
    for (int mt = 0; mt < MT; ++mt)
      af[mt] = *(const bf16x8*)&As[(wrow * MT * 16 + mt * 16 + l16) * LDR + quad * 8];
#pragma unroll
    for (int nt = 0; nt < NT; ++nt)
      bfr[nt] = *(const bf16x8*)&Bs[(wcol * NT * 16 + nt * 16 + l16) * LDR + quad * 8];
#pragma unroll
    for (int mt = 0; mt < MT; ++mt)
#pragma unroll
      for (int nt = 0; nt < NT; ++nt)
        acc[mt][nt] = MFMA16(af[mt], bfr[nt], acc[mt][nt]);
    __syncthreads();
  }
#pragma unroll
  for (int mt = 0; mt < MT; ++mt)
#pragma unroll
    for (int nt = 0; nt < NT; ++nt)
#pragma unroll
      for (int r = 0; r < 4; ++r) {
        const long row = m0 + wrow * MT * 16 + mt * 16 + quad * 4 + r;
        const long col = n0 + wcol * NT * 16 + nt * 16 + l16;
        C[row * (long)N + col] = acc[mt][nt][r];
      }
}

// ---- causal flash attention, split-precision scores.
// Q/K: [B*H][S][64] f32. V: [B*H][S][64] bf16. Out att: [B][S][1024] bf16.
__global__ __launch_bounds__(256) void k_attn(
    const float* __restrict__ Qg, const float* __restrict__ Kg,
    const bf16* __restrict__ Vg, bf16* __restrict__ Og) {
  __shared__ __align__(16) bf16 Khi[64 * 72], Klo[64 * 72];  // [key][dh]
  __shared__ __align__(16) bf16 Vts[64 * 72];                // [dh][key]
  __shared__ __align__(16) bf16 Ps[4 * 16 * 72];             // per-wave P
  const int qt = blockIdx.x, bh = blockIdx.y;
  const int b = bh >> 4, hh = bh & 15;
  const int tid = threadIdx.x, wave = tid >> 6, lane = tid & 63;
  const int quad = lane >> 4, l16 = lane & 15;
  const float* Qp = Qg + (long)bh * 1024 * 64;
  const float* Kp = Kg + (long)bh * 1024 * 64;
  const bf16* Vp = Vg + (long)bh * 1024 * 64;
  const int qbase = qt * 64 + wave * 16;
  // Q fragments, split hi/lo (A-layout: row=l16, k=quad*8..+8, slices at k=0/32)
  bf16x8 aqh0, aql0, aqh1, aql1;
  {
    const float* qr = Qp + (long)(qbase + l16) * 64;
    const f32x4 v0 = *(const f32x4*)&qr[quad * 8];
    const f32x4 v1 = *(const f32x4*)&qr[quad * 8 + 4];
    const f32x4 v2 = *(const f32x4*)&qr[32 + quad * 8];
    const f32x4 v3 = *(const f32x4*)&qr[32 + quad * 8 + 4];
#pragma unroll
    for (int j = 0; j < 4; ++j) {
      aqh0[j] = split_hi(v0[j]); aql0[j] = split_lo(v0[j]);
      aqh0[4 + j] = split_hi(v1[j]); aql0[4 + j] = split_lo(v1[j]);
      aqh1[j] = split_hi(v2[j]); aql1[j] = split_lo(v2[j]);
      aqh1[4 + j] = split_hi(v3[j]); aql1[4 + j] = split_lo(v3[j]);
    }
  }
  const f32x4 zero4 = {0.f, 0.f, 0.f, 0.f};
  f32x4 o[4];
  float m_i[4], l_i[4];
#pragma unroll
  for (int nt = 0; nt < 4; ++nt) o[nt] = zero4;
#pragma unroll
  for (int r = 0; r < 4; ++r) { m_i[r] = -1.0e30f; l_i[r] = 0.f; }
  for (int kc = 0; kc <= qt; ++kc) {
    const int kb = kc * 64;
#pragma unroll
    for (int i = 0; i < 4; ++i) {  // K chunk: 64x64 f32 -> hi/lo LDS
      const int c = i * 256 + tid, r = c >> 4, c4 = c & 15;
      const f32x4 v = *(const f32x4*)&Kp[(long)(kb + r) * 64 + c4 * 4];
      bf16x4 h4, l4;
#pragma unroll
      for (int j = 0; j < 4; ++j) { h4[j] = split_hi(v[j]); l4[j] = split_lo(v[j]); }
      *(bf16x4*)&Khi[r * 72 + c4 * 4] = h4;
      *(bf16x4*)&Klo[r * 72 + c4 * 4] = l4;
    }
#pragma unroll
    for (int i = 0; i < 2; ++i) {  // V chunk: bf16, transposed into Vts
      const int c = i * 256 + tid, r = c >> 3, c8 = c & 7;
      const bf16x8 vv = *(const bf16x8*)&Vp[(long)(kb + r) * 64 + c8 * 8];
#pragma unroll
      for (int j = 0; j < 8; ++j) Vts[(c8 * 8 + j) * 72 + r] = vv[j];
    }
    __syncthreads();
    f32x4 sc[4];
#pragma unroll
    for (int ct = 0; ct < 4; ++ct) {
      const int krow = ct * 16 + l16;
      const bf16x8 bh0 = *(const bf16x8*)&Khi[krow * 72 + quad * 8];
      const bf16x8 bh1 = *(const bf16x8*)&Khi[krow * 72 + 32 + quad * 8];
      const bf16x8 bl0 = *(const bf16x8*)&Klo[krow * 72 + quad * 8];
      const bf16x8 bl1 = *(const bf16x8*)&Klo[krow * 72 + 32 + quad * 8];
      f32x4 s = MFMA16(aqh0, bh0, zero4);
      s = MFMA16(aqh1, bh1, s);
      s = MFMA16(aqh0, bl0, s);
      s = MFMA16(aqh1, bl1, s);
      s = MFMA16(aql0, bh0, s);
      s = MFMA16(aql1, bh1, s);
      sc[ct] = s;
    }
    if (kc == qt) {  // diagonal: scale + causal mask
#pragma unroll
      for (int ct = 0; ct < 4; ++ct) {
        const int col = kb + ct * 16 + l16;
#pragma unroll
        for (int r = 0; r < 4; ++r) {
          const int row = qbase + quad * 4 + r;
          const float s = sc[ct][r] * 0.125f;
          sc[ct][r] = (col > row) ? -1.0e30f : s;
        }
      }
    } else {
#pragma unroll
      for (int ct = 0; ct < 4; ++ct)
#pragma unroll
        for (int r = 0; r < 4; ++r) sc[ct][r] *= 0.125f;
    }
    float rmax[4];
#pragma unroll
    for (int r = 0; r < 4; ++r)
      rmax[r] = fmaxf(fmaxf(sc[0][r], sc[1][r]), fmaxf(sc[2][r], sc[3][r]));
#pragma unroll
    for (int off = 1; off < 16; off <<= 1)
#pragma unroll
      for (int r = 0; r < 4; ++r) rmax[r] = fmaxf(rmax[r], __shfl_xor(rmax[r], off));
    float alpha[4], rsum[4];
#pragma unroll
    for (int r = 0; r < 4; ++r) {
      const float mnew = fmaxf(m_i[r], rmax[r]);
      alpha[r] = __expf(m_i[r] - mnew);
      m_i[r] = mnew;
      rsum[r] = 0.f;
    }
#pragma unroll
    for (int ct = 0; ct < 4; ++ct)
#pragma unroll
      for (int r = 0; r < 4; ++r) {
        const float p = __expf(sc[ct][r] - m_i[r]);
        sc[ct][r] = p;
        rsum[r] += p;
      }
#pragma unroll
    for (int off = 1; off < 16; off <<= 1)
#pragma unroll
      for (int r = 0; r < 4; ++r) rsum[r] += __shfl_xor(rsum[r], off);
#pragma unroll
    for (int r = 0; r < 4; ++r) l_i[r] = l_i[r] * alpha[r] + rsum[r];
#pragma unroll
    for (int nt = 0; nt < 4; ++nt)
#pragma unroll
      for (int r = 0; r < 4; ++r) o[nt][r] *= alpha[r];
    // P: C-layout -> LDS -> A-layout
#pragma unroll
    for (int ct = 0; ct < 4; ++ct)
#pragma unroll
      for (int r = 0; r < 4; ++r)
        Ps[wave * 1152 + (quad * 4 + r) * 72 + ct * 16 + l16] = (bf16)sc[ct][r];
    __syncthreads();
    const bf16x8 ap0 = *(const bf16x8*)&Ps[wave * 1152 + l16 * 72 + quad * 8];
    const bf16x8 ap1 = *(const bf16x8*)&Ps[wave * 1152 + l16 * 72 + 32 + quad * 8];
#pragma unroll
    for (int nt = 0; nt < 4; ++nt) {
      const bf16x8 bv0 = *(const bf16x8*)&Vts[(nt * 16 + l16) * 72 + quad * 8];
      const bf16x8 bv1 = *(const bf16x8*)&Vts[(nt * 16 + l16) * 72 + 32 + quad * 8];
      o[nt] = MFMA16(ap0, bv0, o[nt]);
      o[nt] = MFMA16(ap1, bv1, o[nt]);
    }
    __syncthreads();
  }
  float inv[4];
#pragma unroll
  for (int r = 0; r < 4; ++r) inv[r] = 1.f / l_i[r];
#pragma unroll
  for (int nt = 0; nt < 4; ++nt)
#pragma unroll
    for (int r = 0; r < 4; ++r) {
      const int row = qbase + quad * 4 + r;
      Og[((long)b * 1024 + row) * 1024 + hh * 64 + nt * 16 + l16] =
          (bf16)(o[nt][r] * inv[r]);
    }
}

extern "C" void kernel_launch(void* const* d_in, const int* in_sizes, int n_in,
                              void* d_out, int out_size, void* d_ws, size_t ws_size,
                              hipStream_t stream) {
  const float* x = (const float*)d_in[0];
  const float* cw = (const float*)d_in[1];
  const int* cidx = (const int*)d_in[2];
  const float* wq = (const float*)d_in[3];
  const int* iq = (const int*)d_in[4];
  const float* wk = (const float*)d_in[5];
  const int* ik = (const int*)d_in[6];
  const float* wv = (const float*)d_in[7];
  const int* iv = (const int*)d_in[8];
  const float* neurons = (const float*)d_in[9];
  const float* pool = (const float*)d_in[10];
  const float* WO = (const float*)d_in[11];
  float* out = (float*)d_out;
  char* ws = (char*)d_ws;
  // Workspace (86 MB peak, lifetime-overlapped):
  //   [ 0,32) Kf   f32 [8][16][1024][64]
  //   [32,48) V    bf16
  //   [48,64) att  bf16  -- prep overlay: Wc f32 [48,52), Wn f32 [52,64)
  //   [64,68) WcT  f32
  //   [68,80) Wt   f32 [24][1024][128]
  //   [80,84) h    f32 [8][1024][128]
  //   [84,86) WOb  bf16
  //   Q f32 lives in d_out (exactly 32 MB), dead before the final f32 write.
  float* Kf = (float*)(ws + (0l << 20));
  bf16* V = (bf16*)(ws + (32l << 20));
  bf16* att = (bf16*)(ws + (48l << 20));
  float* Wc = (float*)(ws + (48l << 20));
  float* Wn = (float*)(ws + (52l << 20));
  float* WcT = (float*)(ws + (64l << 20));
  float* Wt = (float*)(ws + (68l << 20));
  float* h = (float*)(ws + (80l << 20));
  bf16* WOb = (bf16*)(ws + (84l << 20));
  float* Q = (float*)d_out;

  k_cvt<<<1024, 256, 0, stream>>>(WO, WOb, 1024l * 1024);
  k_build_wc<<<dim3(1024, 8), 128, 0, stream>>>(neurons, cw, cidx, Wc);
  k_build_mix<<<dim3(4, 128, 24), 256, 0, stream>>>(pool, wq, iq, wk, ik, wv, iv, Wn);
  k_transpose<float><<<dim3(2, 16, 8), 256, 0, stream>>>(Wc, WcT, 1024, 128);
  k_transpose<float><<<dim3(16, 2, 24), 256, 0, stream>>>(Wn, Wt, 128, 1024);
  // h[b] = x[b] (1024x1024) * Wc[b] (1024x128), split-precision, f32 out
  k_gemm_split<<<dim3(2, 16, 8), 256, 0, stream>>>(
      x, WcT, h, 1024, 128, 1024, 1l << 20, 1l << 17, 1l << 17, 0, 1);
  // Q/K (f32, head-split) and V (bf16, head-split): [z] = h[z] * Wt[which*8+z]
  k_gemm_split<<<dim3(16, 16, 8), 256, 0, stream>>>(
      h, Wt, Q, 1024, 1024, 128, 1l << 17, 1l << 17, 1l << 20, 1, 1);
  k_gemm_split<<<dim3(16, 16, 8), 256, 0, stream>>>(
      h, Wt + (8l << 17), Kf, 1024, 1024, 128, 1l << 17, 1l << 17, 1l << 20, 1, 1);
  k_gemm_split<<<dim3(16, 16, 8), 256, 0, stream>>>(
      h, Wt + (16l << 17), V, 1024, 1024, 128, 1l << 17, 1l << 17, 1l << 20, 1, 0);
  k_attn<<<dim3(16, 128), 256, 0, stream>>>(Q, Kf, V, att);
  // out(f32, 8192x1024) = att * W_O^T (W_O [d_out][d_in] is already Bt layout)
  k_gemm_bt<128, 128><<<dim3(8, 64, 1), 256, 0, stream>>>(att, WOb, out, 8192, 1024, 1024);
}

// Round 7
// 406.736 us; speedup vs baseline: 1.2176x; 1.2176x over previous
//
#include <hip/hip_runtime.h>

typedef __bf16 bf16;
typedef __bf16 bf16x4 __attribute__((ext_vector_type(4)));
typedef __bf16 bf16x8 __attribute__((ext_vector_type(8)));
typedef float f32x4 __attribute__((ext_vector_type(4)));

__device__ __forceinline__ f32x4 MFMA16(bf16x8 a, bf16x8 b, f32x4 c) {
  return __builtin_amdgcn_mfma_f32_16x16x32_bf16(a, b, c, 0, 0, 0);
}

__device__ __forceinline__ bf16 split_hi(float v) { return (bf16)v; }
__device__ __forceinline__ bf16 split_lo(float v) { return (bf16)(v - (float)(bf16)v); }

// ---- f32 -> bf16 bulk convert ----
__global__ void k_cvt(const float* __restrict__ in, bf16* __restrict__ out, long n) {
  const long i = ((long)blockIdx.x * 256 + threadIdx.x) * 4;
  if (i < n) {
    const f32x4 v = *(const f32x4*)&in[i];
    bf16x4 o;
#pragma unroll
    for (int j = 0; j < 4; ++j) o[j] = (bf16)v[j];
    *(bf16x4*)&out[i] = o;
  }
}

// ---- Wc[b][d][r] = sum_k w[b,k] * neurons[idx[b,k]][d][r]  (f32 out) ----
__global__ void k_build_wc(const float* __restrict__ neurons, const float* __restrict__ w,
                           const int* __restrict__ idx, float* __restrict__ Wc) {
  const int d = blockIdx.x, b = blockIdx.y, r = threadIdx.x;
  float acc = 0.f;
#pragma unroll
  for (int k = 0; k < 16; ++k) {
    const float wk = w[b * 16 + k];
    const int ni = idx[b * 16 + k];
    acc += wk * neurons[((long)ni * 1024 + d) * 128 + r];
  }
  Wc[((long)b * 1024 + d) * 128 + r] = acc;
}

// ---- Wn[z=which*8+b][r][d] = sum_k w[b,k] * pool[idx[b,k]][r][d]  (f32 out) ----
__global__ void k_build_mix(const float* __restrict__ pool,
                            const float* __restrict__ wq, const int* __restrict__ iq,
                            const float* __restrict__ wk, const int* __restrict__ ik,
                            const float* __restrict__ wv, const int* __restrict__ iv,
                            float* __restrict__ Wn) {
  const int d = blockIdx.x * 256 + threadIdx.x;
  const int r = blockIdx.y;
  const int z = blockIdx.z, which = z >> 3, b = z & 7;
  const float* wp = which == 0 ? wq : (which == 1 ? wk : wv);
  const int* ip = which == 0 ? iq : (which == 1 ? ik : iv);
  float acc = 0.f;
#pragma unroll
  for (int k = 0; k < 8; ++k) {
    const float wkk = wp[b * 8 + k];
    const int ni = ip[b * 8 + k];
    acc += wkk * pool[((long)ni * 128 + r) * 1024 + d];
  }
  Wn[((long)z * 128 + r) * 1024 + d] = acc;
}

// ---- batched transpose [M][N] -> [N][M] (z = batch) ----
template <typename T>
__global__ void k_transpose(const T* __restrict__ in, T* __restrict__ out, int M, int N) {
  __shared__ T t[64][65];
  const int n0 = blockIdx.x * 64, m0 = blockIdx.y * 64;
  const long base = (long)blockIdx.z * M * N;
  const int tid = threadIdx.x;
#pragma unroll
  for (int i = 0; i < 16; ++i) {
    const int lin = i * 256 + tid;
    const int r = lin >> 6, c = lin & 63;
    t[r][c] = in[base + (long)(m0 + r) * N + (n0 + c)];
  }
  __syncthreads();
#pragma unroll
  for (int i = 0; i < 16; ++i) {
    const int lin = i * 256 + tid;
    const int r = lin >> 6, c = lin & 63;
    out[base + (long)(n0 + r) * M + (m0 + c)] = t[c][r];
  }
}

// ---- split-precision GEMM: C = A(MxK,f32) * Bt[n][k](f32), scaled.
// mode: 0 = bf16 out, 1 = f32 out, 2 = split-pair bf16 out (C=hi, C2=lo).
// split_heads: C[(col/64)][row][col%64] per 64-col head. BM=BN=64, 4 waves 2x2.
__global__ __launch_bounds__(256) void k_gemm_split(
    const float* __restrict__ A, const float* __restrict__ Bt, void* __restrict__ C,
    bf16* __restrict__ C2, int M, int N, int K, long sA, long sB, long sC,
    int split_heads, int mode, float scale) {
  constexpr int BM = 64, BN = 64, BK = 32, LDR = 40;
  __shared__ __align__(16) bf16 Ash[BM * LDR], Asl[BM * LDR];
  __shared__ __align__(16) bf16 Bsh[BN * LDR], Bsl[BN * LDR];
  const int tid = threadIdx.x, wave = tid >> 6, lane = tid & 63;
  const int quad = lane >> 4, l16 = lane & 15;
  const int wrow = wave >> 1, wcol = wave & 1;
  const int z = blockIdx.z;
  const float* Ap = A + (long)z * sA;
  const float* Bp = Bt + (long)z * sB;
  const long m0 = (long)blockIdx.y * BM, n0 = (long)blockIdx.x * BN;
  f32x4 acc[2][2];
#pragma unroll
  for (int mt = 0; mt < 2; ++mt)
#pragma unroll
    for (int nt = 0; nt < 2; ++nt) acc[mt][nt] = (f32x4){0.f, 0.f, 0.f, 0.f};
  for (int k0 = 0; k0 < K; k0 += BK) {
#pragma unroll
    for (int i = 0; i < 2; ++i) {
      const int c = i * 256 + tid, r = c >> 3, c4 = c & 7;
      const f32x4 v = *(const f32x4*)&Ap[(m0 + r) * K + k0 + c4 * 4];
      bf16x4 h4, l4;
#pragma unroll
      for (int j = 0; j < 4; ++j) { h4[j] = split_hi(v[j]); l4[j] = split_lo(v[j]); }
      *(bf16x4*)&Ash[r * LDR + c4 * 4] = h4;
      *(bf16x4*)&Asl[r * LDR + c4 * 4] = l4;
    }
#pragma unroll
    for (int i = 0; i < 2; ++i) {
      const int c = i * 256 + tid, r = c >> 3, c4 = c & 7;
      const f32x4 v = *(const f32x4*)&Bp[(n0 + r) * K + k0 + c4 * 4];
      bf16x4 h4, l4;
#pragma unroll
      for (int j = 0; j < 4; ++j) { h4[j] = split_hi(v[j]); l4[j] = split_lo(v[j]); }
      *(bf16x4*)&Bsh[r * LDR + c4 * 4] = h4;
      *(bf16x4*)&Bsl[r * LDR + c4 * 4] = l4;
    }
    __syncthreads();
    bf16x8 ah[2], al[2], bh[2], bl[2];
#pragma unroll
    for (int mt = 0; mt < 2; ++mt) {
      const int row = wrow * 32 + mt * 16 + l16;
      ah[mt] = *(const bf16x8*)&Ash[row * LDR + quad * 8];
      al[mt] = *(const bf16x8*)&Asl[row * LDR + quad * 8];
    }
#pragma unroll
    for (int nt = 0; nt < 2; ++nt) {
      const int row = wcol * 32 + nt * 16 + l16;
      bh[nt] = *(const bf16x8*)&Bsh[row * LDR + quad * 8];
      bl[nt] = *(const bf16x8*)&Bsl[row * LDR + quad * 8];
    }
#pragma unroll
    for (int mt = 0; mt < 2; ++mt)
#pragma unroll
      for (int nt = 0; nt < 2; ++nt) {
        acc[mt][nt] = MFMA16(ah[mt], bh[nt], acc[mt][nt]);
        acc[mt][nt] = MFMA16(ah[mt], bl[nt], acc[mt][nt]);
        acc[mt][nt] = MFMA16(al[mt], bh[nt], acc[mt][nt]);
      }
    __syncthreads();
  }
  bf16* Cb = (bf16*)C + (long)z * sC;
  float* Cf = (float*)C + (long)z * sC;
  bf16* C2b = C2 + (long)z * sC;
#pragma unroll
  for (int mt = 0; mt < 2; ++mt)
#pragma unroll
    for (int nt = 0; nt < 2; ++nt)
#pragma unroll
      for (int r = 0; r < 4; ++r) {
        const long row = m0 + wrow * 32 + mt * 16 + quad * 4 + r;
        const long col = n0 + wcol * 32 + nt * 16 + l16;
        const float v = acc[mt][nt][r] * scale;
        const long off = split_heads
                             ? ((col >> 6) * ((long)M * 64) + row * 64 + (col & 63))
                             : (row * (long)N + col);
        if (mode == 1) {
          Cf[off] = v;
        } else if (mode == 0) {
          Cb[off] = (bf16)v;
        } else {
          const bf16 hi = (bf16)v;
          Cb[off] = hi;
          C2b[off] = (bf16)(v - (float)hi);
        }
      }
}

// ---- plain bf16 GEMM (output projection): C = A(MxK) * Bt[n][k], out f32. ----
template <int BM, int BN>
__global__ __launch_bounds__(256) void k_gemm_bt(
    const bf16* __restrict__ A, const bf16* __restrict__ Bt, float* __restrict__ C,
    int M, int N, int K) {
  constexpr int BK = 32, LDR = BK + 8;
  constexpr int MT = BM / 32, NT = BN / 32;
  __shared__ __align__(16) bf16 As[BM * LDR];
  __shared__ __align__(16) bf16 Bs[BN * LDR];
  const int tid = threadIdx.x, wave = tid >> 6, lane = tid & 63;
  const int quad = lane >> 4, l16 = lane & 15;
  const int wrow = wave >> 1, wcol = wave & 1;
  const long m0 = (long)blockIdx.y * BM, n0 = (long)blockIdx.x * BN;
  f32x4 acc[MT][NT];
#pragma unroll
  for (int mt = 0; mt < MT; ++mt)
#pragma unroll
    for (int nt = 0; nt < NT; ++nt) acc[mt][nt] = (f32x4){0.f, 0.f, 0.f, 0.f};
  constexpr int ACH = BM * BK / 8 / 256;
  constexpr int BCH = BN * BK / 8 / 256;
  for (int k0 = 0; k0 < K; k0 += BK) {
#pragma unroll
    for (int i = 0; i < ACH; ++i) {
      const int c = i * 256 + tid, r = c >> 2, c4 = c & 3;
      *(bf16x8*)&As[r * LDR + c4 * 8] = *(const bf16x8*)&A[(m0 + r) * K + k0 + c4 * 8];
    }
#pragma unroll
    for (int i = 0; i < BCH; ++i) {
      const int c = i * 256 + tid, r = c >> 2, c4 = c & 3;
      *(bf16x8*)&Bs[r * LDR + c4 * 8] = *(const bf16x8*)&Bt[(n0 + r) * K + k0 + c4 * 8];
    }
    __syncthreads();
    bf16x8 af[MT], bfr[NT];
#pragma unroll
    for (int mt = 0; mt < MT; ++mt)
      af[mt] = *(const bf16x8*)&As[(wrow * MT * 16 + mt * 16 + l16) * LDR + quad * 8];
#pragma unroll
    for (int nt = 0; nt < NT; ++nt)
      bfr[nt] = *(const bf16x8*)&Bs[(wcol * NT * 16 + nt * 16 + l16) * LDR + quad * 8];
#pragma unroll
    for (int mt = 0; mt < MT; ++mt)
#pragma unroll
      for (int nt = 0; nt < NT; ++nt)
        acc[mt][nt] = MFMA16(af[mt], bfr[nt], acc[mt][nt]);
    __syncthreads();
  }
#pragma unroll
  for (int mt = 0; mt < MT; ++mt)
#pragma unroll
    for (int nt = 0; nt < NT; ++nt)
#pragma unroll
      for (int r = 0; r < 4; ++r) {
        const long row = m0 + wrow * MT * 16 + mt * 16 + quad * 4 + r;
        const long col = n0 + wcol * NT * 16 + nt * 16 + l16;
        C[row * (long)N + col] = acc[mt][nt][r];
      }
}

// ---- causal flash attention, pre-split bf16 Q/K, pre-transposed V.
// Qhi/Qlo/Khi/Klo: [B*H][S][64] bf16 (Q pre-scaled by 1/8). Vt: [B][16][64][S] bf16.
// Out att: [B][S][1024] bf16. Block: 4 waves x 32 q-rows = 128 q-rows. Grid (8, B*H).
__global__ __launch_bounds__(256, 3) void k_attn(
    const bf16* __restrict__ Qhi, const bf16* __restrict__ Qlo,
    const bf16* __restrict__ Khi, const bf16* __restrict__ Klo,
    const bf16* __restrict__ Vtg, bf16* __restrict__ Og) {
  __shared__ __align__(16) bf16 KhiS[64 * 72], KloS[64 * 72];  // [key][dh]
  __shared__ __align__(16) bf16 VtS[64 * 72];                  // [dh][key]
  __shared__ __align__(16) bf16 Ps[4 * 32 * 72];               // per-wave P [qrow][key]
  const int qt = blockIdx.x, bh = blockIdx.y;
  const int b = bh >> 4, hh = bh & 15;
  const int tid = threadIdx.x, wave = tid >> 6, lane = tid & 63;
  const int quad = lane >> 4, l16 = lane & 15;
  const long bhS = (long)bh * 1024 * 64;
  const bf16* KhiG = Khi + bhS;
  const bf16* KloG = Klo + bhS;
  const bf16* VtG = Vtg + (long)bh * 64 * 1024;
  const int qbw = qt * 128 + wave * 32;  // this wave's first q-row
  // Q fragments (A-layout), 2 row-tiles x 2 k-slices x hi/lo
  bf16x8 qh[2][2], ql[2][2];
#pragma unroll
  for (int m = 0; m < 2; ++m) {
    const long rq = (long)(qbw + m * 16 + l16) * 64;
#pragma unroll
    for (int s = 0; s < 2; ++s) {
      qh[m][s] = *(const bf16x8*)&Qhi[bhS + rq + s * 32 + quad * 8];
      ql[m][s] = *(const bf16x8*)&Qlo[bhS + rq + s * 32 + quad * 8];
    }
  }
  const f32x4 zero4 = {0.f, 0.f, 0.f, 0.f};
  f32x4 o[2][4];
  float m_i[2][4], l_i[2][4];
#pragma unroll
  for (int m = 0; m < 2; ++m) {
#pragma unroll
    for (int nt = 0; nt < 4; ++nt) o[m][nt] = zero4;
#pragma unroll
    for (int r = 0; r < 4; ++r) { m_i[m][r] = -1.0e30f; l_i[m][r] = 0.f; }
  }
  const int nchunks = qt * 2 + 2;
  for (int kc = 0; kc < nchunks; ++kc) {
    const int kb = kc * 64;
#pragma unroll
    for (int i = 0; i < 2; ++i) {  // stage K hi/lo [key][dh] and V^T [dh][key]
      const int c = i * 256 + tid, r = c >> 3, c8 = c & 7;
      *(bf16x8*)&KhiS[r * 72 + c8 * 8] = *(const bf16x8*)&KhiG[(long)(kb + r) * 64 + c8 * 8];
      *(bf16x8*)&KloS[r * 72 + c8 * 8] = *(const bf16x8*)&KloG[(long)(kb + r) * 64 + c8 * 8];
      *(bf16x8*)&VtS[r * 72 + c8 * 8] = *(const bf16x8*)&VtG[(long)r * 1024 + kb + c8 * 8];
    }
    __syncthreads();
    if (kb <= qbw + 31) {  // this wave has unmasked keys in this chunk
      f32x4 sc[2][4];
#pragma unroll
      for (int ct = 0; ct < 4; ++ct) {
        const int krow = ct * 16 + l16;
        const bf16x8 kh0 = *(const bf16x8*)&KhiS[krow * 72 + quad * 8];
        const bf16x8 kh1 = *(const bf16x8*)&KhiS[krow * 72 + 32 + quad * 8];
        const bf16x8 kl0 = *(const bf16x8*)&KloS[krow * 72 + quad * 8];
        const bf16x8 kl1 = *(const bf16x8*)&KloS[krow * 72 + 32 + quad * 8];
#pragma unroll
        for (int m = 0; m < 2; ++m) {
          f32x4 s = MFMA16(qh[m][0], kh0, zero4);
          s = MFMA16(qh[m][1], kh1, s);
          s = MFMA16(qh[m][0], kl0, s);
          s = MFMA16(qh[m][1], kl1, s);
          s = MFMA16(ql[m][0], kh0, s);
          s = MFMA16(ql[m][1], kh1, s);
          sc[m][ct] = s;
        }
      }
      if (kb + 63 > qbw) {  // diagonal region: causal mask
#pragma unroll
        for (int ct = 0; ct < 4; ++ct) {
          const int col = kb + ct * 16 + l16;
#pragma unroll
          for (int m = 0; m < 2; ++m)
#pragma unroll
            for (int r = 0; r < 4; ++r) {
              const int row = qbw + m * 16 + quad * 4 + r;
              if (col > row) sc[m][ct][r] = -1.0e30f;
            }
        }
      }
#pragma unroll
      for (int m = 0; m < 2; ++m) {
        float rmax[4], alpha[4], rsum[4];
#pragma unroll
        for (int r = 0; r < 4; ++r)
          rmax[r] = fmaxf(fmaxf(sc[m][0][r], sc[m][1][r]), fmaxf(sc[m][2][r], sc[m][3][r]));
#pragma unroll
        for (int off = 1; off < 16; off <<= 1)
#pragma unroll
          for (int r = 0; r < 4; ++r) rmax[r] = fmaxf(rmax[r], __shfl_xor(rmax[r], off));
#pragma unroll
        for (int r = 0; r < 4; ++r) {
          const float mnew = fmaxf(m_i[m][r], rmax[r]);
          alpha[r] = __expf(m_i[m][r] - mnew);
          m_i[m][r] = mnew;
          rsum[r] = 0.f;
        }
#pragma unroll
        for (int ct = 0; ct < 4; ++ct)
#pragma unroll
          for (int r = 0; r < 4; ++r) {
            const float p = __expf(sc[m][ct][r] - m_i[m][r]);
            sc[m][ct][r] = p;
            rsum[r] += p;
          }
#pragma unroll
        for (int off = 1; off < 16; off <<= 1)
#pragma unroll
          for (int r = 0; r < 4; ++r) rsum[r] += __shfl_xor(rsum[r], off);
#pragma unroll
        for (int r = 0; r < 4; ++r) l_i[m][r] = l_i[m][r] * alpha[r] + rsum[r];
#pragma unroll
        for (int nt = 0; nt < 4; ++nt)
#pragma unroll
          for (int r = 0; r < 4; ++r) o[m][nt][r] *= alpha[r];
        // P: C-layout -> per-wave LDS -> A-layout
#pragma unroll
        for (int ct = 0; ct < 4; ++ct)
#pragma unroll
          for (int r = 0; r < 4; ++r)
            Ps[wave * 2304 + (m * 16 + quad * 4 + r) * 72 + ct * 16 + l16] =
                (bf16)sc[m][ct][r];
      }
      bf16x8 ap[2][2];
#pragma unroll
      for (int m = 0; m < 2; ++m) {
        ap[m][0] = *(const bf16x8*)&Ps[wave * 2304 + (m * 16 + l16) * 72 + quad * 8];
        ap[m][1] = *(const bf16x8*)&Ps[wave * 2304 + (m * 16 + l16) * 72 + 32 + quad * 8];
      }
#pragma unroll
      for (int nt = 0; nt < 4; ++nt) {
        const bf16x8 bv0 = *(const bf16x8*)&VtS[(nt * 16 + l16) * 72 + quad * 8];
        const bf16x8 bv1 = *(const bf16x8*)&VtS[(nt * 16 + l16) * 72 + 32 + quad * 8];
#pragma unroll
        for (int m = 0; m < 2; ++m) {
          o[m][nt] = MFMA16(ap[m][0], bv0, o[m][nt]);
          o[m][nt] = MFMA16(ap[m][1], bv1, o[m][nt]);
        }
      }
    }
    __syncthreads();
  }
#pragma unroll
  for (int m = 0; m < 2; ++m) {
    float inv[4];
#pragma unroll
    for (int r = 0; r < 4; ++r) inv[r] = 1.f / l_i[m][r];
#pragma unroll
    for (int nt = 0; nt < 4; ++nt)
#pragma unroll
      for (int r = 0; r < 4; ++r) {
        const int row = qbw + m * 16 + quad * 4 + r;
        Og[((long)b * 1024 + row) * 1024 + hh * 64 + nt * 16 + l16] =
            (bf16)(o[m][nt][r] * inv[r]);
      }
  }
}

extern "C" void kernel_launch(void* const* d_in, const int* in_sizes, int n_in,
                              void* d_out, int out_size, void* d_ws, size_t ws_size,
                              hipStream_t stream) {
  const float* x = (const float*)d_in[0];
  const float* cw = (const float*)d_in[1];
  const int* cidx = (const int*)d_in[2];
  const float* wq = (const float*)d_in[3];
  const int* iq = (const int*)d_in[4];
  const float* wk = (const float*)d_in[5];
  const int* ik = (const int*)d_in[6];
  const float* wv = (const float*)d_in[7];
  const int* iv = (const int*)d_in[8];
  const float* neurons = (const float*)d_in[9];
  const float* pool = (const float*)d_in[10];
  const float* WO = (const float*)d_in[11];
  float* out = (float*)d_out;
  char* ws = (char*)d_ws;
  // Workspace (86 MB peak, lifetime-overlapped):
  //   [ 0,16) Khi bf16 [8][16][1024][64]
  //   [16,32) Klo bf16
  //   [32,48) Vt  bf16 [8][16][64][1024]
  //   [48,64) att bf16  -- prep overlay: Wc f32 [48,52), Wn f32 [52,64)
  //   [64,68) WcT f32
  //   [68,80) Wt  f32 [24][1024][128]
  //   [80,84) h   f32 [8][1024][128]
  //   [84,86) WOb bf16
  //   Qhi/Qlo bf16 in d_out (2 x 16 MB), dead before the final f32 write.
  bf16* Khi = (bf16*)(ws + (0l << 20));
  bf16* Klo = (bf16*)(ws + (16l << 20));
  bf16* Vt = (bf16*)(ws + (32l << 20));
  bf16* att = (bf16*)(ws + (48l << 20));
  float* Wc = (float*)(ws + (48l << 20));
  float* Wn = (float*)(ws + (52l << 20));
  float* WcT = (float*)(ws + (64l << 20));
  float* Wt = (float*)(ws + (68l << 20));
  float* h = (float*)(ws + (80l << 20));
  bf16* WOb = (bf16*)(ws + (84l << 20));
  bf16* Qhi = (bf16*)d_out;
  bf16* Qlo = (bf16*)d_out + (8l << 20);

  k_cvt<<<1024, 256, 0, stream>>>(WO, WOb, 1024l * 1024);
  k_build_wc<<<dim3(1024, 8), 128, 0, stream>>>(neurons, cw, cidx, Wc);
  k_build_mix<<<dim3(4, 128, 24), 256, 0, stream>>>(pool, wq, iq, wk, ik, wv, iv, Wn);
  k_transpose<float><<<dim3(2, 16, 8), 256, 0, stream>>>(Wc, WcT, 1024, 128);
  k_transpose<float><<<dim3(16, 2, 24), 256, 0, stream>>>(Wn, Wt, 128, 1024);
  // h[b] = x[b] (1024x1024) * Wc[b] (1024x128), split-precision, f32 out
  k_gemm_split<<<dim3(2, 16, 8), 256, 0, stream>>>(
      x, WcT, h, nullptr, 1024, 128, 1024, 1l << 20, 1l << 17, 1l << 17, 0, 1, 1.f);
  // Q = (h*Wq)/8 pre-split into Qhi/Qlo (head-split layout)
  k_gemm_split<<<dim3(16, 16, 8), 256, 0, stream>>>(
      h, Wt, Qhi, Qlo, 1024, 1024, 128, 1l << 17, 1l << 17, 1l << 20, 1, 2, 0.125f);
  // K pre-split into Khi/Klo (head-split layout)
  k_gemm_split<<<dim3(16, 16, 8), 256, 0, stream>>>(
      h, Wt + (8l << 17), Khi, Klo, 1024, 1024, 128, 1l << 17, 1l << 17, 1l << 20, 1, 2, 1.f);
  // V^T directly: Vt[z] = Wt_V[z] (1024d x 128r) * h[z]^T -> [d][s] == [16][64][1024]
  k_gemm_split<<<dim3(16, 16, 8), 256, 0, stream>>>(
      Wt + (16l << 17), h, Vt, nullptr, 1024, 1024, 128, 1l << 17, 1l << 17, 1l << 20, 0, 0, 1.f);
  k_attn<<<dim3(8, 128), 256, 0, stream>>>(Qhi, Qlo, Khi, Klo, Vt, att);
  // out(f32, 8192x1024) = att * W_O^T (W_O [d_out][d_in] is already Bt layout)
  k_gemm_bt<128, 128><<<dim3(8, 64, 1), 256, 0, stream>>>(att, WOb, out, 8192, 1024, 1024);
}